// Round 12
// baseline (282.871 us; speedup 1.0000x reference)
//
#include <hip/hip_runtime.h>
#include <hip/hip_bf16.h>

typedef __attribute__((ext_vector_type(4))) float f32x4;
typedef __attribute__((ext_vector_type(8))) short s16x8;

typedef const __attribute__((address_space(1))) void* gptr_t;
typedef __attribute__((address_space(3))) void* lptr_t;

__device__ __forceinline__ short f2b(float f){ __hip_bfloat16 h=__float2bfloat16(f); return *(short*)&h; }
__device__ __forceinline__ float b2f(short s){ __hip_bfloat16 h; *(short*)&h = s; return __bfloat162float(h); }

__device__ __forceinline__ void gl_lds16(const void* g, void* l){
  __builtin_amdgcn_global_load_lds((gptr_t)g, (lptr_t)l, 16, 0, 0);
}

// ---------------- fused prep: cvt_x | cvt_wt3 | gpack (block-range dispatch) ----------------
__global__ __launch_bounds__(256) void prep_all(const float* __restrict__ X, short* __restrict__ Xb,
      const float* __restrict__ Wq, const float* __restrict__ Wk, const float* __restrict__ Wv,
      short* __restrict__ WT, const int* __restrict__ g, unsigned* __restrict__ gb){
  __shared__ short tile[64][72];
  int b = blockIdx.x; int t = threadIdx.x;
  if (b < 384){
    int i = b*256 + t;
    const float4* p = (const float4*)(X + (size_t)i*8);
    float4 a = p[0], c = p[1];
    s16x8 o;
    o[0]=f2b(a.x); o[1]=f2b(a.y); o[2]=f2b(a.z); o[3]=f2b(a.w);
    o[4]=f2b(c.x); o[5]=f2b(c.y); o[6]=f2b(c.z); o[7]=f2b(c.w);
    *(s16x8*)(Xb + (size_t)i*8) = o;
  } else if (b < 816){
    int bx2 = b - 384;
    int mat = bx2 / 144; int bx = bx2 % 144;
    const float* W = mat==0?Wq:(mat==1?Wk:Wv);
    short* O = WT + (size_t)mat*768*768;
    int bl = bx % 12, bn = bx / 12;
    int l0 = bl*64, n0 = bn*64;
    #pragma unroll
    for (int p=0;p<4;p++){
      int lr = p*16 + (t>>4);
      int nc = (t&15)*4;
      float4 v = *(const float4*)(W + (size_t)(l0+lr)*768 + n0 + nc);
      tile[lr][nc+0]=f2b(v.x); tile[lr][nc+1]=f2b(v.y); tile[lr][nc+2]=f2b(v.z); tile[lr][nc+3]=f2b(v.w);
    }
    __syncthreads();
    #pragma unroll
    for (int p=0;p<2;p++){
      int nr = p*32 + (t>>3);
      int lc = (t&7)*8;
      s16x8 o;
      #pragma unroll
      for(int u=0;u<8;u++) o[u] = tile[lc+u][nr];
      *(s16x8*)(O + (size_t)(n0+nr)*768 + l0 + lc) = o;
    }
  } else {
    int w = (b-816)*256 + t;
    const int* p = g + (size_t)w*32;
    unsigned bm=0;
    #pragma unroll
    for(int i=0;i<32;i++) bm |= (p[i]>0 ? 1u:0u) << i;
    gb[w]=bm;
  }
}

__global__ __launch_bounds__(256) void vtrans(const short* __restrict__ vs, short* __restrict__ vT){
  __shared__ short tile[64][72];
  int h = blockIdx.y; int i0 = blockIdx.x*64;
  int t = threadIdx.x;
  #pragma unroll
  for(int p=0;p<2;p++){
    int ir = p*32 + (t>>3); int c8=(t&7)*8;
    *(s16x8*)&tile[ir][c8] = *(const s16x8*)(vs + (size_t)(i0+ir)*768 + h*64 + c8);
  }
  __syncthreads();
  #pragma unroll
  for(int p=0;p<2;p++){
    int dr = p*32 + (t>>3); int i8=(t&7)*8;
    s16x8 o;
    #pragma unroll
    for(int u=0;u<8;u++) o[u]=tile[i8+u][dr];
    *(s16x8*)(vT + ((size_t)h*64 + dr)*1024 + i0 + i8) = o;
  }
}

// ---------------- QKV projection GEMM (2-phase dbuf, K=768) ----------------
__global__ __launch_bounds__(256) void qkv_gemm(const short* __restrict__ Xb, const short* __restrict__ WT,
      const float* __restrict__ bq, const float* __restrict__ bk, const float* __restrict__ bv,
      short* __restrict__ qs, short* __restrict__ ks, short* __restrict__ vs){
  __shared__ short lA[2][4096], lB[2][4096];
  int mat = blockIdx.y;
  const short* B = WT + (size_t)mat*768*768;
  const float* bias = mat==0?bq:(mat==1?bk:bv);
  short* outp = mat==0?qs:(mat==1?ks:vs);
  float scale = mat==0 ? 0.125f : 1.0f;
  int tm = (blockIdx.x / 6)*128, tn = (blockIdx.x % 6)*128;
  int t=threadIdx.x, wave=t>>6, lane=t&63;
  int srow=t>>2, scol=(t&3)*8;
  int wm=(wave>>1)*64, wn=(wave&1)*64;
  int krow=(lane>>4)*8, rl=lane&15;
  const short* pA0 = Xb + (size_t)(tm+srow)*768 + scol;
  const short* pA1 = pA0 + (size_t)64*768;
  const short* pB0 = B + (size_t)(tn+srow)*768 + scol;
  const short* pB1 = pB0 + (size_t)64*768;
  f32x4 acc[4][4]={};
  gl_lds16(pA0, &lA[0][wave*512]);
  gl_lds16(pA1, &lA[0][2048 + wave*512]);
  gl_lds16(pB0, &lB[0][wave*512]);
  gl_lds16(pB1, &lB[0][2048 + wave*512]);
  pA0+=32; pA1+=32; pB0+=32; pB1+=32;
  __syncthreads();
  int cur=0;
  #pragma unroll 1
  for (int k0=32;k0<768;k0+=32){
    gl_lds16(pA0, &lA[cur^1][wave*512]);
    gl_lds16(pA1, &lA[cur^1][2048 + wave*512]);
    gl_lds16(pB0, &lB[cur^1][wave*512]);
    gl_lds16(pB1, &lB[cur^1][2048 + wave*512]);
    pA0+=32; pA1+=32; pB0+=32; pB1+=32;
    s16x8 af[4], bfr[4];
    #pragma unroll
    for(int m=0;m<4;m++) af[m] = *(s16x8*)&lA[cur][(wm+m*16+rl)*32 + krow];
    #pragma unroll
    for(int n=0;n<4;n++) bfr[n] = *(s16x8*)&lB[cur][(wn+n*16+rl)*32 + krow];
    __builtin_amdgcn_s_setprio(1);
    #pragma unroll
    for(int m=0;m<4;m++)
      #pragma unroll
      for(int n=0;n<4;n++)
        acc[m][n]=__builtin_amdgcn_mfma_f32_16x16x32_bf16(af[m],bfr[n],acc[m][n],0,0,0);
    __builtin_amdgcn_s_setprio(0);
    __syncthreads();
    cur^=1;
  }
  { s16x8 af[4], bfr[4];
    #pragma unroll
    for(int m=0;m<4;m++) af[m] = *(s16x8*)&lA[cur][(wm+m*16+rl)*32 + krow];
    #pragma unroll
    for(int n=0;n<4;n++) bfr[n] = *(s16x8*)&lB[cur][(wn+n*16+rl)*32 + krow];
    __builtin_amdgcn_s_setprio(1);
    #pragma unroll
    for(int m=0;m<4;m++)
      #pragma unroll
      for(int n=0;n<4;n++)
        acc[m][n]=__builtin_amdgcn_mfma_f32_16x16x32_bf16(af[m],bfr[n],acc[m][n],0,0,0);
    __builtin_amdgcn_s_setprio(0);
  }
  int r0 = tm + wm + (lane>>4)*4, c0 = tn + wn + (lane&15);
  #pragma unroll
  for(int m=0;m<4;m++)
    #pragma unroll
    for(int n=0;n<4;n++){
      int col = c0 + n*16; float bb = bias[col];
      #pragma unroll
      for(int r=0;r<4;r++){
        int row = r0 + m*16 + r;
        outp[(size_t)row*768 + col] = f2b((acc[m][n][r] + bb)*scale);
      }
    }
}

// ---------------- W_G = exp(K Q^T) masked (bitmask), + row sums ----------------
__global__ __launch_bounds__(256) void wg_gemm(const short* __restrict__ kb, const short* __restrict__ qb,
      const unsigned* __restrict__ gb, const float* __restrict__ am,
      short* __restrict__ WG, float* __restrict__ od){
  __shared__ short lK[128*64], lQ[128*64];
  int h=blockIdx.y;
  int tm=(blockIdx.x>>3)*128, tn=(blockIdx.x&7)*128;
  int t=threadIdx.x, wave=t>>6, lane=t&63;
  int srow=t>>3, scol=(t&7)*8;
  int wm=(wave>>1)*64, wn=(wave&1)*64;
  #pragma unroll
  for(int r=0;r<4;++r){
    gl_lds16(kb + (size_t)(tm+srow+r*32)*768 + h*64 + scol, lK + r*2048 + wave*512);
    gl_lds16(qb + (size_t)(tn+srow+r*32)*768 + h*64 + scol, lQ + r*2048 + wave*512);
  }
  __syncthreads();
  int rl=lane&15;
  f32x4 acc[4][4]={};
  #pragma unroll
  for(int ks=0;ks<2;ks++){
    int krow=ks*32+(lane>>4)*8;
    s16x8 af[4], bfr[4];
    #pragma unroll
    for(int m=0;m<4;m++) af[m]=*(s16x8*)&lK[(wm+m*16+rl)*64+krow];
    #pragma unroll
    for(int n=0;n<4;n++) bfr[n]=*(s16x8*)&lQ[(wn+n*16+rl)*64+krow];
    #pragma unroll
    for(int m=0;m<4;m++)
      #pragma unroll
      for(int n=0;n<4;n++)
        acc[m][n]=__builtin_amdgcn_mfma_f32_16x16x32_bf16(af[m],bfr[n],acc[m][n],0,0,0);
  }
  size_t hm=(size_t)h<<20;
  int r0=tm+wm+(lane>>4)*4, c0=tn+wn+rl;
  #pragma unroll
  for(int m=0;m<4;m++){
    float rs[4]={0.f,0.f,0.f,0.f};
    #pragma unroll
    for(int n=0;n<4;n++){
      int col=c0+n*16;
      bool mc = am[col] >= 0.0f;
      unsigned sh = col & 31; int wofs = col >> 5;
      #pragma unroll
      for(int r=0;r<4;r++){
        int row=r0+m*16+r;
        float e = __expf(acc[m][n][r]);
        bool gbit = (gb[(row<<5) + wofs] >> sh) & 1u;
        float w = (gbit && am[row]>=0.0f && mc) ? e : 0.f;
        WG[hm+(size_t)row*1024+col]=f2b(w);
        rs[r]+=w;
      }
    }
    #pragma unroll
    for(int r=0;r<4;r++){
      float s=rs[r];
      #pragma unroll
      for(int off=1;off<16;off<<=1) s+=__shfl_xor(s,off);
      if(rl==0) atomicAdd(&od[(h<<10)+r0+m*16+r], s);
    }
  }
}

__global__ void rhos_k(const float* __restrict__ od, float* __restrict__ rhos){
  __shared__ float red[256];
  int h = blockIdx.x, t = threadIdx.x;
  float m = -1e30f;
  for (int i=t;i<1024;i+=256) m = fmaxf(m, od[(h<<10)+i]);
  red[t]=m; __syncthreads();
  for(int s=128;s>0;s>>=1){ if(t<s) red[t]=fmaxf(red[t],red[t+s]); __syncthreads(); }
  if(t==0) rhos[h]=red[0];
}

// Am = (WG + diag(rho-od))/rho ; AmT = Am^T ; T = b7*Am + b6*I
__global__ __launch_bounds__(256) void amat_t(const short* __restrict__ WG, const float* __restrict__ od,
      const float* __restrict__ rhos, short* __restrict__ Am, short* __restrict__ AmT,
      short* __restrict__ T){
  __shared__ short tile[64][72];
  const float b7 = -33.f/2048.f, b6 = -21.f/1024.f;
  int h = blockIdx.y; int bx = blockIdx.x;
  int rb = bx >> 4, cb = bx & 15;
  int r0 = rb*64, c0 = cb*64;
  float rho = rhos[h]; float inv = 1.0f/fmaxf(rho,1e-30f);
  size_t hm = (size_t)h<<20;
  int t = threadIdx.x;
  #pragma unroll
  for(int p=0;p<2;p++){
    int r = p*32 + (t>>3); int c8 = (t&7)*8;
    size_t base = hm + (size_t)(r0+r)*1024 + c0 + c8;
    s16x8 w = *(const s16x8*)(WG + base);
    s16x8 oa, ot;
    float dadd = (rho - od[(h<<10)+r0+r])*inv;
    #pragma unroll
    for(int u=0;u<8;u++){
      bool dg = (rb==cb) && ((c8+u)==r);
      float a = b2f(w[u])*inv + (dg ? dadd : 0.f);
      oa[u]=f2b(a);
      ot[u]=f2b(b7*a + (dg ? b6 : 0.f));
      tile[r][c8+u]=oa[u];
    }
    *(s16x8*)(Am+base)=oa; *(s16x8*)(T+base)=ot;
  }
  __syncthreads();
  #pragma unroll
  for(int p=0;p<2;p++){
    int c = p*32 + (t>>3); int r8 = (t&7)*8;
    s16x8 o;
    #pragma unroll
    for(int u=0;u<8;u++) o[u]=tile[r8+u][c];
    *(s16x8*)(AmT + hm + (size_t)(c0+c)*1024 + r0 + r8) = o;
  }
}

// ======== big GEMMs: 128^2 tile, double-buffered BK=32 (proven structure), T1 swizzle. ========
// Split macro: HEAD (indices) / PIPE (staging + K-loop) so epi kernels can insert
// warm-prefetch loads between them (hidden under the K-loop, anchored after it).
#define GEMM2P_HEAD \
  __shared__ short lA[2][4096], lB[2][4096]; \
  int wg = ((int)blockIdx.x & 7)*96 + ((int)blockIdx.x >> 3); \
  int h = wg >> 6; int tile = wg & 63; \
  int tm=(tile>>3)*128, tn=(tile&7)*128; \
  size_t hm=(size_t)h<<20; \
  const short* Ag = A + hm; const short* Bg = B + hm; \
  int t=threadIdx.x, wave=t>>6, lane=t&63; \
  int srow=t>>2, scol=(t&3)*8; \
  int wm=(wave>>1)*64, wn=(wave&1)*64; \
  int krow=(lane>>4)*8, rl=lane&15;

#define GEMM2P_PIPE \
  const short* pA0 = Ag + (size_t)(tm+srow)*1024 + scol; \
  const short* pA1 = pA0 + (size_t)64*1024; \
  const short* pB0 = Bg + (size_t)(tn+srow)*1024 + scol; \
  const short* pB1 = pB0 + (size_t)64*1024; \
  f32x4 acc[4][4]={}; \
  gl_lds16(pA0, &lA[0][wave*512]); \
  gl_lds16(pA1, &lA[0][2048 + wave*512]); \
  gl_lds16(pB0, &lB[0][wave*512]); \
  gl_lds16(pB1, &lB[0][2048 + wave*512]); \
  pA0+=32; pA1+=32; pB0+=32; pB1+=32; \
  __syncthreads(); \
  int cur=0; \
  _Pragma("unroll 1") \
  for(int k0=32;k0<1024;k0+=32){ \
    gl_lds16(pA0, &lA[cur^1][wave*512]); \
    gl_lds16(pA1, &lA[cur^1][2048 + wave*512]); \
    gl_lds16(pB0, &lB[cur^1][wave*512]); \
    gl_lds16(pB1, &lB[cur^1][2048 + wave*512]); \
    pA0+=32; pA1+=32; pB0+=32; pB1+=32; \
    s16x8 af[4], bfr[4]; \
    _Pragma("unroll") \
    for(int m=0;m<4;m++) af[m]=*(s16x8*)&lA[cur][(wm+m*16+rl)*32+krow]; \
    _Pragma("unroll") \
    for(int n=0;n<4;n++) bfr[n]=*(s16x8*)&lB[cur][(wn+n*16+rl)*32+krow]; \
    __builtin_amdgcn_s_setprio(1); \
    _Pragma("unroll") \
    for(int m=0;m<4;m++) \
      _Pragma("unroll") \
      for(int n=0;n<4;n++) \
        acc[m][n]=__builtin_amdgcn_mfma_f32_16x16x32_bf16(af[m],bfr[n],acc[m][n],0,0,0); \
    __builtin_amdgcn_s_setprio(0); \
    __syncthreads(); \
    cur^=1; \
  } \
  { s16x8 af[4], bfr[4]; \
    _Pragma("unroll") \
    for(int m=0;m<4;m++) af[m]=*(s16x8*)&lA[cur][(wm+m*16+rl)*32+krow]; \
    _Pragma("unroll") \
    for(int n=0;n<4;n++) bfr[n]=*(s16x8*)&lB[cur][(wn+n*16+rl)*32+krow]; \
    __builtin_amdgcn_s_setprio(1); \
    _Pragma("unroll") \
    for(int m=0;m<4;m++) \
      _Pragma("unroll") \
      for(int n=0;n<4;n++) \
        acc[m][n]=__builtin_amdgcn_mfma_f32_16x16x32_bf16(af[m],bfr[n],acc[m][n],0,0,0); \
    __builtin_amdgcn_s_setprio(0); \
  } \
  int r0=tm+wm+(lane>>4)*4, c0=tn+wn+(lane&15);

__global__ __launch_bounds__(256) void gemm2p_plain(const short* __restrict__ A, const short* __restrict__ B,
      short* __restrict__ D){
  GEMM2P_HEAD
  GEMM2P_PIPE
  short* Dg = D + hm;
  #pragma unroll
  for(int m=0;m<4;m++)
    #pragma unroll
    for(int n=0;n<4;n++){
      int col=c0+n*16;
      #pragma unroll
      for(int r=0;r<4;r++)
        Dg[(size_t)(r0+m*16+r)*1024 + col]=f2b(acc[m][n][r]);
    }
}

__global__ __launch_bounds__(256) void gemm2p_epi(const short* __restrict__ A, const short* __restrict__ B,
      short* __restrict__ D, const short* __restrict__ E1, const short* __restrict__ E2,
      float c0c, float cA, float cB){
  GEMM2P_HEAD
  const short* E1g = E1 + hm; const short* E2g = E2 + hm;
  short* Dg = D + hm;
  // warm-prefetch the epilogue tiles (E1,E2,D; both 64B sectors of each 128B row-half)
  s16x8 w0,w1,w2,w3,w4,w5;
  {
    size_t wofs = (size_t)(tm + (t>>1))*1024 + tn + (size_t)(t&1)*64;
    w0 = *(const s16x8*)(E1g + wofs); w1 = *(const s16x8*)(E1g + wofs + 32);
    w2 = *(const s16x8*)(E2g + wofs); w3 = *(const s16x8*)(E2g + wofs + 32);
    w4 = *(const s16x8*)(Dg  + wofs); w5 = *(const s16x8*)(Dg  + wofs + 32);
  }
  GEMM2P_PIPE
  asm volatile("" :: "v"(w0), "v"(w1), "v"(w2), "v"(w3), "v"(w4), "v"(w5));
  #pragma unroll
  for(int m=0;m<4;m++)
    #pragma unroll
    for(int n=0;n<4;n++){
      int col=c0+n*16;
      #pragma unroll
      for(int r=0;r<4;r++){
        int row=r0+m*16+r;
        size_t e = (size_t)row*1024 + col;
        float v = acc[m][n][r] + cA*b2f(E1g[e]) + cB*b2f(E2g[e]);
        if(row==col) v += c0c;
        Dg[e]=f2b(v);
      }
    }
}

__global__ __launch_bounds__(256) void gemm2p_epi_stat(const short* __restrict__ A, const short* __restrict__ B,
      short* __restrict__ D, const short* __restrict__ E1, const short* __restrict__ E2,
      float c0c, float cA, float cB, float* __restrict__ rowabs, float* __restrict__ dvp){
  GEMM2P_HEAD
  const short* E1g = E1 + hm; const short* E2g = E2 + hm;
  short* Dg = D + hm;
  s16x8 w0,w1,w2,w3,w4,w5;
  {
    size_t wofs = (size_t)(tm + (t>>1))*1024 + tn + (size_t)(t&1)*64;
    w0 = *(const s16x8*)(E1g + wofs); w1 = *(const s16x8*)(E1g + wofs + 32);
    w2 = *(const s16x8*)(E2g + wofs); w3 = *(const s16x8*)(E2g + wofs + 32);
    w4 = *(const s16x8*)(Dg  + wofs); w5 = *(const s16x8*)(Dg  + wofs + 32);
  }
  GEMM2P_PIPE
  asm volatile("" :: "v"(w0), "v"(w1), "v"(w2), "v"(w3), "v"(w4), "v"(w5));
  #pragma unroll
  for(int m=0;m<4;m++){
    float rs[4]={0.f,0.f,0.f,0.f};
    #pragma unroll
    for(int n=0;n<4;n++){
      int col=c0+n*16;
      #pragma unroll
      for(int r=0;r<4;r++){
        int row=r0+m*16+r;
        size_t e = (size_t)row*1024 + col;
        float v = acc[m][n][r] + cA*b2f(E1g[e]) + cB*b2f(E2g[e]);
        if(row==col){ v += c0c; dvp[(h<<10)+row] = v; }
        rs[r] += fabsf(v);
        Dg[e]=f2b(v);
      }
    }
    #pragma unroll
    for(int r=0;r<4;r++){
      float s=rs[r];
      #pragma unroll
      for(int off=1;off<16;off<<=1) s+=__shfl_xor(s,off);
      if(rl==0) atomicAdd(&rowabs[(h<<10)+r0+m*16+r], s);
    }
  }
}

// ---------------- final: attn = .8*(WG/od)@v + .2*(d_i v_i - L@v)/r_i ----------------
__global__ __launch_bounds__(256) void attn_k(const short* __restrict__ WG, const short* __restrict__ L,
    const short* __restrict__ vT, const short* __restrict__ vs,
    const float* __restrict__ od, const float* __restrict__ dv, const float* __restrict__ rowabs,
    float* __restrict__ out){
  __shared__ short lW[64*32], lL[64*32], lV[64*32];
  int h=blockIdx.y, tm=blockIdx.x*64;
  size_t hm=(size_t)h<<20;
  int t=threadIdx.x, wave=t>>6, lane=t&63;
  int srow=t>>2, scol=(t&3)*8;
  f32x4 a1[4]={}, a2[4]={};
  for(int j0=0;j0<1024;j0+=32){
    gl_lds16(WG + hm + (size_t)(tm+srow)*1024 + j0 + scol, lW + wave*512);
    gl_lds16(L  + hm + (size_t)(tm+srow)*1024 + j0 + scol, lL + wave*512);
    gl_lds16(vT + ((size_t)h*64 + srow)*1024 + j0 + scol, lV + wave*512);
    __syncthreads();
    int krow=(lane>>4)*8, rl=lane&15;
    s16x8 fw, fl, fv[4];
    fw=*(s16x8*)&lW[(wave*16+rl)*32+krow];
    fl=*(s16x8*)&lL[(wave*16+rl)*32+krow];
    #pragma unroll
    for(int n=0;n<4;n++) fv[n]=*(s16x8*)&lV[(n*16+rl)*32+krow];
    #pragma unroll
    for(int n=0;n<4;n++){
      a1[n]=__builtin_amdgcn_mfma_f32_16x16x32_bf16(fw,fv[n],a1[n],0,0,0);
      a2[n]=__builtin_amdgcn_mfma_f32_16x16x32_bf16(fl,fv[n],a2[n],0,0,0);
    }
    __syncthreads();
  }
  #pragma unroll
  for(int r=0;r<4;r++){
    int row = tm + wave*16 + (lane>>4)*4 + r;
    float invod = 1.0f/fmaxf(od[(h<<10)+row], 1e-12f);
    float dvi = dv[(h<<10)+row];
    float ivr = 1.0f/fmaxf(rowabs[(h<<10)+row] - fabsf(dvi), 1e-12f);
    #pragma unroll
    for(int n=0;n<4;n++){
      int d = n*16 + (lane&15);
      float vv = b2f(vs[(size_t)row*768 + h*64 + d]);
      out[(((size_t)h<<10)+row)*64 + d] = 0.8f*a1[n][r]*invod + 0.2f*(dvi*vv - a2[n][r])*ivr;
    }
  }
}

// ---------------- launch ----------------
extern "C" void kernel_launch(void* const* d_in, const int* in_sizes, int n_in,
                              void* d_out, int out_size, void* d_ws, size_t ws_size,
                              hipStream_t stream){
  const float* hs = (const float*)d_in[0];
  const float* Wq = (const float*)d_in[1];
  const float* bq = (const float*)d_in[2];
  const float* Wk = (const float*)d_in[3];
  const float* bk = (const float*)d_in[4];
  const float* Wv = (const float*)d_in[5];
  const float* bv = (const float*)d_in[6];
  const int*   g  = (const int*)d_in[7];
  const float* am = (const float*)d_in[8];
  float* out = (float*)d_out;

  char* w = (char*)d_ws;
  auto alloc=[&](size_t bytes)->char*{ char* p=w; w += (bytes+255)&~(size_t)255; return p; };
  short* Xb  = (short*)alloc((size_t)1024*768*2);
  short* WT  = (short*)alloc((size_t)3*768*768*2);
  short* qs  = (short*)alloc((size_t)1024*768*2);
  short* ks  = (short*)alloc((size_t)1024*768*2);
  short* vs  = (short*)alloc((size_t)1024*768*2);
  short* vT  = (short*)alloc((size_t)12*64*1024*2);
  unsigned* gb = (unsigned*)alloc((size_t)1024*32*4);
  short* WG  = (short*)alloc((size_t)12*1024*1024*2);
  short* Am  = (short*)alloc((size_t)12*1024*1024*2);
  short* AmT = (short*)alloc((size_t)12*1024*1024*2);  // later reused as V
  short* Tm  = (short*)alloc((size_t)12*1024*1024*2);  // later reused as L
  short* A2  = (short*)alloc((size_t)12*1024*1024*2);
  short* A3T = (short*)alloc((size_t)12*1024*1024*2);
  float* od  = (float*)alloc((size_t)2*12*1024*4);     // od + rab contiguous, one memset
  float* rab = od + 12*1024;
  float* rh  = (float*)alloc((size_t)64*4);
  float* dv  = (float*)alloc((size_t)12*1024*4);

  hipMemsetAsync(od, 0, (size_t)2*12*1024*4, stream);

  prep_all<<<944,256,0,stream>>>(hs, Xb, Wq, Wk, Wv, WT, g, gb);
  qkv_gemm<<<dim3(48,3),256,0,stream>>>(Xb, WT, bq,bk,bv, qs,ks,vs);
  vtrans<<<dim3(16,12),256,0,stream>>>(vs, vT);
  wg_gemm<<<dim3(64,12),256,0,stream>>>(ks, qs, gb, am, WG, od);
  rhos_k<<<12,256,0,stream>>>(od, rh);
  amat_t<<<dim3(256,12),256,0,stream>>>(WG, od, rh, Am, AmT, Tm);

  const float b1=-0.5f, b2=-0.125f, b3=-1.f/16.f, b4=-5.f/128.f, b5=-7.f/256.f;
  short* V = AmT;   // AmT dead after G2
  short* L = Tm;    // Tm dead after G3
  // G1: A2 = Am * AmT^T (= A^2)
  gemm2p_plain<<<768,256,0,stream>>>(Am, AmT, A2);
  // G2: A3T = AmT * A2^T (= (A^3)^T)
  gemm2p_plain<<<768,256,0,stream>>>(AmT, A2, A3T);
  // G3: V = T * A3 + b3 I + b4 A + b5 A2
  gemm2p_epi<<<768,256,0,stream>>>(Tm, A3T, V, Am, A2, b3,b4,b5);
  // G4: L = V * A3 + I + b1 A + b2 A2   (+ fused row |L| sums and diagonal)
  gemm2p_epi_stat<<<768,256,0,stream>>>(V, A3T, L, Am, A2, 1.0f,b1,b2, rab, dv);

  attn_k<<<dim3(16,12),256,0,stream>>>(WG, L, vT, vs, od, dv, rab, out);
}

// Round 13
// 280.655 us; speedup vs baseline: 1.0079x; 1.0079x over previous
//
#include <hip/hip_runtime.h>
#include <hip/hip_bf16.h>

typedef __attribute__((ext_vector_type(4))) float f32x4;
typedef __attribute__((ext_vector_type(8))) short s16x8;

typedef const __attribute__((address_space(1))) void* gptr_t;
typedef __attribute__((address_space(3))) void* lptr_t;

__device__ __forceinline__ short f2b(float f){ __hip_bfloat16 h=__float2bfloat16(f); return *(short*)&h; }
__device__ __forceinline__ float b2f(short s){ __hip_bfloat16 h; *(short*)&h = s; return __bfloat162float(h); }

__device__ __forceinline__ void gl_lds16(const void* g, void* l){
  __builtin_amdgcn_global_load_lds((gptr_t)g, (lptr_t)l, 16, 0, 0);
}

// ---------------- fused prep: cvt_x | cvt_wt3 | gpack (block-range dispatch) ----------------
__global__ __launch_bounds__(256) void prep_all(const float* __restrict__ X, short* __restrict__ Xb,
      const float* __restrict__ Wq, const float* __restrict__ Wk, const float* __restrict__ Wv,
      short* __restrict__ WT, const int* __restrict__ g, unsigned* __restrict__ gb){
  __shared__ short tile[64][72];
  int b = blockIdx.x; int t = threadIdx.x;
  if (b < 384){
    int i = b*256 + t;
    const float4* p = (const float4*)(X + (size_t)i*8);
    float4 a = p[0], c = p[1];
    s16x8 o;
    o[0]=f2b(a.x); o[1]=f2b(a.y); o[2]=f2b(a.z); o[3]=f2b(a.w);
    o[4]=f2b(c.x); o[5]=f2b(c.y); o[6]=f2b(c.z); o[7]=f2b(c.w);
    *(s16x8*)(Xb + (size_t)i*8) = o;
  } else if (b < 816){
    int bx2 = b - 384;
    int mat = bx2 / 144; int bx = bx2 % 144;
    const float* W = mat==0?Wq:(mat==1?Wk:Wv);
    short* O = WT + (size_t)mat*768*768;
    int bl = bx % 12, bn = bx / 12;
    int l0 = bl*64, n0 = bn*64;
    #pragma unroll
    for (int p=0;p<4;p++){
      int lr = p*16 + (t>>4);
      int nc = (t&15)*4;
      float4 v = *(const float4*)(W + (size_t)(l0+lr)*768 + n0 + nc);
      tile[lr][nc+0]=f2b(v.x); tile[lr][nc+1]=f2b(v.y); tile[lr][nc+2]=f2b(v.z); tile[lr][nc+3]=f2b(v.w);
    }
    __syncthreads();
    #pragma unroll
    for (int p=0;p<2;p++){
      int nr = p*32 + (t>>3);
      int lc = (t&7)*8;
      s16x8 o;
      #pragma unroll
      for(int u=0;u<8;u++) o[u] = tile[lc+u][nr];
      *(s16x8*)(O + (size_t)(n0+nr)*768 + l0 + lc) = o;
    }
  } else {
    int w = (b-816)*256 + t;
    const int* p = g + (size_t)w*32;
    unsigned bm=0;
    #pragma unroll
    for(int i=0;i<32;i++) bm |= (p[i]>0 ? 1u:0u) << i;
    gb[w]=bm;
  }
}

__global__ __launch_bounds__(256) void vtrans(const short* __restrict__ vs, short* __restrict__ vT){
  __shared__ short tile[64][72];
  int h = blockIdx.y; int i0 = blockIdx.x*64;
  int t = threadIdx.x;
  #pragma unroll
  for(int p=0;p<2;p++){
    int ir = p*32 + (t>>3); int c8=(t&7)*8;
    *(s16x8*)&tile[ir][c8] = *(const s16x8*)(vs + (size_t)(i0+ir)*768 + h*64 + c8);
  }
  __syncthreads();
  #pragma unroll
  for(int p=0;p<2;p++){
    int dr = p*32 + (t>>3); int i8=(t&7)*8;
    s16x8 o;
    #pragma unroll
    for(int u=0;u<8;u++) o[u]=tile[i8+u][dr];
    *(s16x8*)(vT + ((size_t)h*64 + dr)*1024 + i0 + i8) = o;
  }
}

// ---------------- QKV projection GEMM (2-phase dbuf, K=768) ----------------
__global__ __launch_bounds__(256) void qkv_gemm(const short* __restrict__ Xb, const short* __restrict__ WT,
      const float* __restrict__ bq, const float* __restrict__ bk, const float* __restrict__ bv,
      short* __restrict__ qs, short* __restrict__ ks, short* __restrict__ vs){
  __shared__ short lA[2][4096], lB[2][4096];
  int mat = blockIdx.y;
  const short* B = WT + (size_t)mat*768*768;
  const float* bias = mat==0?bq:(mat==1?bk:bv);
  short* outp = mat==0?qs:(mat==1?ks:vs);
  float scale = mat==0 ? 0.125f : 1.0f;
  int tm = (blockIdx.x / 6)*128, tn = (blockIdx.x % 6)*128;
  int t=threadIdx.x, wave=t>>6, lane=t&63;
  int srow=t>>2, scol=(t&3)*8;
  int wm=(wave>>1)*64, wn=(wave&1)*64;
  int krow=(lane>>4)*8, rl=lane&15;
  const short* pA0 = Xb + (size_t)(tm+srow)*768 + scol;
  const short* pA1 = pA0 + (size_t)64*768;
  const short* pB0 = B + (size_t)(tn+srow)*768 + scol;
  const short* pB1 = pB0 + (size_t)64*768;
  f32x4 acc[4][4]={};
  gl_lds16(pA0, &lA[0][wave*512]);
  gl_lds16(pA1, &lA[0][2048 + wave*512]);
  gl_lds16(pB0, &lB[0][wave*512]);
  gl_lds16(pB1, &lB[0][2048 + wave*512]);
  pA0+=32; pA1+=32; pB0+=32; pB1+=32;
  __syncthreads();
  int cur=0;
  #pragma unroll 1
  for (int k0=32;k0<768;k0+=32){
    gl_lds16(pA0, &lA[cur^1][wave*512]);
    gl_lds16(pA1, &lA[cur^1][2048 + wave*512]);
    gl_lds16(pB0, &lB[cur^1][wave*512]);
    gl_lds16(pB1, &lB[cur^1][2048 + wave*512]);
    pA0+=32; pA1+=32; pB0+=32; pB1+=32;
    s16x8 af[4], bfr[4];
    #pragma unroll
    for(int m=0;m<4;m++) af[m] = *(s16x8*)&lA[cur][(wm+m*16+rl)*32 + krow];
    #pragma unroll
    for(int n=0;n<4;n++) bfr[n] = *(s16x8*)&lB[cur][(wn+n*16+rl)*32 + krow];
    __builtin_amdgcn_s_setprio(1);
    #pragma unroll
    for(int m=0;m<4;m++)
      #pragma unroll
      for(int n=0;n<4;n++)
        acc[m][n]=__builtin_amdgcn_mfma_f32_16x16x32_bf16(af[m],bfr[n],acc[m][n],0,0,0);
    __builtin_amdgcn_s_setprio(0);
    __syncthreads();
    cur^=1;
  }
  { s16x8 af[4], bfr[4];
    #pragma unroll
    for(int m=0;m<4;m++) af[m] = *(s16x8*)&lA[cur][(wm+m*16+rl)*32 + krow];
    #pragma unroll
    for(int n=0;n<4;n++) bfr[n] = *(s16x8*)&lB[cur][(wn+n*16+rl)*32 + krow];
    __builtin_amdgcn_s_setprio(1);
    #pragma unroll
    for(int m=0;m<4;m++)
      #pragma unroll
      for(int n=0;n<4;n++)
        acc[m][n]=__builtin_amdgcn_mfma_f32_16x16x32_bf16(af[m],bfr[n],acc[m][n],0,0,0);
    __builtin_amdgcn_s_setprio(0);
  }
  int r0 = tm + wm + (lane>>4)*4, c0 = tn + wn + (lane&15);
  #pragma unroll
  for(int m=0;m<4;m++)
    #pragma unroll
    for(int n=0;n<4;n++){
      int col = c0 + n*16; float bb = bias[col];
      #pragma unroll
      for(int r=0;r<4;r++){
        int row = r0 + m*16 + r;
        outp[(size_t)row*768 + col] = f2b((acc[m][n][r] + bb)*scale);
      }
    }
}

// ---------------- W_G = exp(K Q^T) masked (bitmask), + row sums ----------------
__global__ __launch_bounds__(256) void wg_gemm(const short* __restrict__ kb, const short* __restrict__ qb,
      const unsigned* __restrict__ gb, const float* __restrict__ am,
      short* __restrict__ WG, float* __restrict__ od){
  __shared__ short lK[128*64], lQ[128*64];
  int h=blockIdx.y;
  int tm=(blockIdx.x>>3)*128, tn=(blockIdx.x&7)*128;
  int t=threadIdx.x, wave=t>>6, lane=t&63;
  int srow=t>>3, scol=(t&7)*8;
  int wm=(wave>>1)*64, wn=(wave&1)*64;
  #pragma unroll
  for(int r=0;r<4;++r){
    gl_lds16(kb + (size_t)(tm+srow+r*32)*768 + h*64 + scol, lK + r*2048 + wave*512);
    gl_lds16(qb + (size_t)(tn+srow+r*32)*768 + h*64 + scol, lQ + r*2048 + wave*512);
  }
  __syncthreads();
  int rl=lane&15;
  f32x4 acc[4][4]={};
  #pragma unroll
  for(int ks=0;ks<2;ks++){
    int krow=ks*32+(lane>>4)*8;
    s16x8 af[4], bfr[4];
    #pragma unroll
    for(int m=0;m<4;m++) af[m]=*(s16x8*)&lK[(wm+m*16+rl)*64+krow];
    #pragma unroll
    for(int n=0;n<4;n++) bfr[n]=*(s16x8*)&lQ[(wn+n*16+rl)*64+krow];
    #pragma unroll
    for(int m=0;m<4;m++)
      #pragma unroll
      for(int n=0;n<4;n++)
        acc[m][n]=__builtin_amdgcn_mfma_f32_16x16x32_bf16(af[m],bfr[n],acc[m][n],0,0,0);
  }
  size_t hm=(size_t)h<<20;
  int r0=tm+wm+(lane>>4)*4, c0=tn+wn+rl;
  #pragma unroll
  for(int m=0;m<4;m++){
    float rs[4]={0.f,0.f,0.f,0.f};
    #pragma unroll
    for(int n=0;n<4;n++){
      int col=c0+n*16;
      bool mc = am[col] >= 0.0f;
      unsigned sh = col & 31; int wofs = col >> 5;
      #pragma unroll
      for(int r=0;r<4;r++){
        int row=r0+m*16+r;
        float e = __expf(acc[m][n][r]);
        bool gbit = (gb[(row<<5) + wofs] >> sh) & 1u;
        float w = (gbit && am[row]>=0.0f && mc) ? e : 0.f;
        WG[hm+(size_t)row*1024+col]=f2b(w);
        rs[r]+=w;
      }
    }
    #pragma unroll
    for(int r=0;r<4;r++){
      float s=rs[r];
      #pragma unroll
      for(int off=1;off<16;off<<=1) s+=__shfl_xor(s,off);
      if(rl==0) atomicAdd(&od[(h<<10)+r0+m*16+r], s);
    }
  }
}

__global__ void rhos_k(const float* __restrict__ od, float* __restrict__ rhos){
  __shared__ float red[256];
  int h = blockIdx.x, t = threadIdx.x;
  float m = -1e30f;
  for (int i=t;i<1024;i+=256) m = fmaxf(m, od[(h<<10)+i]);
  red[t]=m; __syncthreads();
  for(int s=128;s>0;s>>=1){ if(t<s) red[t]=fmaxf(red[t],red[t+s]); __syncthreads(); }
  if(t==0) rhos[h]=red[0];
}

// Am = (WG + diag(rho-od))/rho ; AmT = Am^T ; T = b7*Am + b6*I
__global__ __launch_bounds__(256) void amat_t(const short* __restrict__ WG, const float* __restrict__ od,
      const float* __restrict__ rhos, short* __restrict__ Am, short* __restrict__ AmT,
      short* __restrict__ T){
  __shared__ short tile[64][72];
  const float b7 = -33.f/2048.f, b6 = -21.f/1024.f;
  int h = blockIdx.y; int bx = blockIdx.x;
  int rb = bx >> 4, cb = bx & 15;
  int r0 = rb*64, c0 = cb*64;
  float rho = rhos[h]; float inv = 1.0f/fmaxf(rho,1e-30f);
  size_t hm = (size_t)h<<20;
  int t = threadIdx.x;
  #pragma unroll
  for(int p=0;p<2;p++){
    int r = p*32 + (t>>3); int c8 = (t&7)*8;
    size_t base = hm + (size_t)(r0+r)*1024 + c0 + c8;
    s16x8 w = *(const s16x8*)(WG + base);
    s16x8 oa, ot;
    float dadd = (rho - od[(h<<10)+r0+r])*inv;
    #pragma unroll
    for(int u=0;u<8;u++){
      bool dg = (rb==cb) && ((c8+u)==r);
      float a = b2f(w[u])*inv + (dg ? dadd : 0.f);
      oa[u]=f2b(a);
      ot[u]=f2b(b7*a + (dg ? b6 : 0.f));
      tile[r][c8+u]=oa[u];
    }
    *(s16x8*)(Am+base)=oa; *(s16x8*)(T+base)=ot;
  }
  __syncthreads();
  #pragma unroll
  for(int p=0;p<2;p++){
    int c = p*32 + (t>>3); int r8 = (t&7)*8;
    s16x8 o;
    #pragma unroll
    for(int u=0;u<8;u++) o[u]=tile[r8+u][c];
    *(s16x8*)(AmT + hm + (size_t)(c0+c)*1024 + r0 + r8) = o;
  }
}

// ======== big GEMMs: 128^2 tile, double-buffered BK=32 (proven best structure), ========
// ======== T1 XCD swizzle, bump-pointer staging addresses.                        ========
#define GEMM2P_PROLOG \
  __shared__ short lA[2][4096], lB[2][4096]; \
  int wg = ((int)blockIdx.x & 7)*96 + ((int)blockIdx.x >> 3); \
  int h = wg >> 6; int tile = wg & 63; \
  int tm=(tile>>3)*128, tn=(tile&7)*128; \
  size_t hm=(size_t)h<<20; \
  const short* Ag = A + hm; const short* Bg = B + hm; \
  int t=threadIdx.x, wave=t>>6, lane=t&63; \
  int srow=t>>2, scol=(t&3)*8; \
  int wm=(wave>>1)*64, wn=(wave&1)*64; \
  int krow=(lane>>4)*8, rl=lane&15; \
  const short* pA0 = Ag + (size_t)(tm+srow)*1024 + scol; \
  const short* pA1 = pA0 + (size_t)64*1024; \
  const short* pB0 = Bg + (size_t)(tn+srow)*1024 + scol; \
  const short* pB1 = pB0 + (size_t)64*1024; \
  f32x4 acc[4][4]={}; \
  gl_lds16(pA0, &lA[0][wave*512]); \
  gl_lds16(pA1, &lA[0][2048 + wave*512]); \
  gl_lds16(pB0, &lB[0][wave*512]); \
  gl_lds16(pB1, &lB[0][2048 + wave*512]); \
  pA0+=32; pA1+=32; pB0+=32; pB1+=32; \
  __syncthreads(); \
  int cur=0; \
  _Pragma("unroll 1") \
  for(int k0=32;k0<1024;k0+=32){ \
    gl_lds16(pA0, &lA[cur^1][wave*512]); \
    gl_lds16(pA1, &lA[cur^1][2048 + wave*512]); \
    gl_lds16(pB0, &lB[cur^1][wave*512]); \
    gl_lds16(pB1, &lB[cur^1][2048 + wave*512]); \
    pA0+=32; pA1+=32; pB0+=32; pB1+=32; \
    s16x8 af[4], bfr[4]; \
    _Pragma("unroll") \
    for(int m=0;m<4;m++) af[m]=*(s16x8*)&lA[cur][(wm+m*16+rl)*32+krow]; \
    _Pragma("unroll") \
    for(int n=0;n<4;n++) bfr[n]=*(s16x8*)&lB[cur][(wn+n*16+rl)*32+krow]; \
    __builtin_amdgcn_s_setprio(1); \
    _Pragma("unroll") \
    for(int m=0;m<4;m++) \
      _Pragma("unroll") \
      for(int n=0;n<4;n++) \
        acc[m][n]=__builtin_amdgcn_mfma_f32_16x16x32_bf16(af[m],bfr[n],acc[m][n],0,0,0); \
    __builtin_amdgcn_s_setprio(0); \
    __syncthreads(); \
    cur^=1; \
  } \
  { s16x8 af[4], bfr[4]; \
    _Pragma("unroll") \
    for(int m=0;m<4;m++) af[m]=*(s16x8*)&lA[cur][(wm+m*16+rl)*32+krow]; \
    _Pragma("unroll") \
    for(int n=0;n<4;n++) bfr[n]=*(s16x8*)&lB[cur][(wn+n*16+rl)*32+krow]; \
    __builtin_amdgcn_s_setprio(1); \
    _Pragma("unroll") \
    for(int m=0;m<4;m++) \
      _Pragma("unroll") \
      for(int n=0;n<4;n++) \
        acc[m][n]=__builtin_amdgcn_mfma_f32_16x16x32_bf16(af[m],bfr[n],acc[m][n],0,0,0); \
    __builtin_amdgcn_s_setprio(0); \
  } \
  int r0=tm+wm+(lane>>4)*4, c0=tn+wn+(lane&15);

__global__ __launch_bounds__(256) void gemm2p_plain(const short* __restrict__ A, const short* __restrict__ B,
      short* __restrict__ D){
  GEMM2P_PROLOG
  short* Dg = D + hm;
  #pragma unroll
  for(int m=0;m<4;m++)
    #pragma unroll
    for(int n=0;n<4;n++){
      int col=c0+n*16;
      #pragma unroll
      for(int r=0;r<4;r++)
        Dg[(size_t)(r0+m*16+r)*1024 + col]=f2b(acc[m][n][r]);
    }
}

__global__ __launch_bounds__(256) void gemm2p_epi(const short* __restrict__ A, const short* __restrict__ B,
      short* __restrict__ D, const short* __restrict__ E1, const short* __restrict__ E2,
      float c0c, float cA, float cB){
  GEMM2P_PROLOG
  short* Dg = D + hm;
  const short* E1g = E1 + hm; const short* E2g = E2 + hm;
  #pragma unroll
  for(int m=0;m<4;m++)
    #pragma unroll
    for(int n=0;n<4;n++){
      int col=c0+n*16;
      #pragma unroll
      for(int r=0;r<4;r++){
        int row=r0+m*16+r;
        size_t e = (size_t)row*1024 + col;
        float v = acc[m][n][r] + cA*b2f(E1g[e]) + cB*b2f(E2g[e]);
        if(row==col) v += c0c;
        Dg[e]=f2b(v);
      }
    }
}

__global__ __launch_bounds__(256) void gemm2p_epi_stat(const short* __restrict__ A, const short* __restrict__ B,
      short* __restrict__ D, const short* __restrict__ E1, const short* __restrict__ E2,
      float c0c, float cA, float cB, float* __restrict__ rowabs, float* __restrict__ dvp){
  GEMM2P_PROLOG
  short* Dg = D + hm;
  const short* E1g = E1 + hm; const short* E2g = E2 + hm;
  #pragma unroll
  for(int m=0;m<4;m++){
    float rs[4]={0.f,0.f,0.f,0.f};
    #pragma unroll
    for(int n=0;n<4;n++){
      int col=c0+n*16;
      #pragma unroll
      for(int r=0;r<4;r++){
        int row=r0+m*16+r;
        size_t e = (size_t)row*1024 + col;
        float v = acc[m][n][r] + cA*b2f(E1g[e]) + cB*b2f(E2g[e]);
        if(row==col){ v += c0c; dvp[(h<<10)+row] = v; }
        rs[r] += fabsf(v);
        Dg[e]=f2b(v);
      }
    }
    #pragma unroll
    for(int r=0;r<4;r++){
      float s=rs[r];
      #pragma unroll
      for(int off=1;off<16;off<<=1) s+=__shfl_xor(s,off);
      if(rl==0) atomicAdd(&rowabs[(h<<10)+r0+m*16+r], s);
    }
  }
}

// ---------------- final: attn = .8*(WG/od)@v + .2*(d_i v_i - L@v)/r_i ----------------
__global__ __launch_bounds__(256) void attn_k(const short* __restrict__ WG, const short* __restrict__ L,
    const short* __restrict__ vT, const short* __restrict__ vs,
    const float* __restrict__ od, const float* __restrict__ dv, const float* __restrict__ rowabs,
    float* __restrict__ out){
  __shared__ short lW[64*32], lL[64*32], lV[64*32];
  int h=blockIdx.y, tm=blockIdx.x*64;
  size_t hm=(size_t)h<<20;
  int t=threadIdx.x, wave=t>>6, lane=t&63;
  int srow=t>>2, scol=(t&3)*8;
  f32x4 a1[4]={}, a2[4]={};
  for(int j0=0;j0<1024;j0+=32){
    gl_lds16(WG + hm + (size_t)(tm+srow)*1024 + j0 + scol, lW + wave*512);
    gl_lds16(L  + hm + (size_t)(tm+srow)*1024 + j0 + scol, lL + wave*512);
    gl_lds16(vT + ((size_t)h*64 + srow)*1024 + j0 + scol, lV + wave*512);
    __syncthreads();
    int krow=(lane>>4)*8, rl=lane&15;
    s16x8 fw, fl, fv[4];
    fw=*(s16x8*)&lW[(wave*16+rl)*32+krow];
    fl=*(s16x8*)&lL[(wave*16+rl)*32+krow];
    #pragma unroll
    for(int n=0;n<4;n++) fv[n]=*(s16x8*)&lV[(n*16+rl)*32+krow];
    #pragma unroll
    for(int n=0;n<4;n++){
      a1[n]=__builtin_amdgcn_mfma_f32_16x16x32_bf16(fw,fv[n],a1[n],0,0,0);
      a2[n]=__builtin_amdgcn_mfma_f32_16x16x32_bf16(fl,fv[n],a2[n],0,0,0);
    }
    __syncthreads();
  }
  #pragma unroll
  for(int r=0;r<4;r++){
    int row = tm + wave*16 + (lane>>4)*4 + r;
    float invod = 1.0f/fmaxf(od[(h<<10)+row], 1e-12f);
    float dvi = dv[(h<<10)+row];
    float ivr = 1.0f/fmaxf(rowabs[(h<<10)+row] - fabsf(dvi), 1e-12f);
    #pragma unroll
    for(int n=0;n<4;n++){
      int d = n*16 + (lane&15);
      float vv = b2f(vs[(size_t)row*768 + h*64 + d]);
      out[(((size_t)h<<10)+row)*64 + d] = 0.8f*a1[n][r]*invod + 0.2f*(dvi*vv - a2[n][r])*ivr;
    }
  }
}

// ---------------- launch ----------------
extern "C" void kernel_launch(void* const* d_in, const int* in_sizes, int n_in,
                              void* d_out, int out_size, void* d_ws, size_t ws_size,
                              hipStream_t stream){
  const float* hs = (const float*)d_in[0];
  const float* Wq = (const float*)d_in[1];
  const float* bq = (const float*)d_in[2];
  const float* Wk = (const float*)d_in[3];
  const float* bk = (const float*)d_in[4];
  const float* Wv = (const float*)d_in[5];
  const float* bv = (const float*)d_in[6];
  const int*   g  = (const int*)d_in[7];
  const float* am = (const float*)d_in[8];
  float* out = (float*)d_out;

  char* w = (char*)d_ws;
  auto alloc=[&](size_t bytes)->char*{ char* p=w; w += (bytes+255)&~(size_t)255; return p; };
  short* Xb  = (short*)alloc((size_t)1024*768*2);
  short* WT  = (short*)alloc((size_t)3*768*768*2);
  short* qs  = (short*)alloc((size_t)1024*768*2);
  short* ks  = (short*)alloc((size_t)1024*768*2);
  short* vs  = (short*)alloc((size_t)1024*768*2);
  short* vT  = (short*)alloc((size_t)12*64*1024*2);
  unsigned* gb = (unsigned*)alloc((size_t)1024*32*4);
  short* WG  = (short*)alloc((size_t)12*1024*1024*2);
  short* Am  = (short*)alloc((size_t)12*1024*1024*2);
  short* AmT = (short*)alloc((size_t)12*1024*1024*2);  // later reused as V
  short* Tm  = (short*)alloc((size_t)12*1024*1024*2);  // later reused as L
  short* A2  = (short*)alloc((size_t)12*1024*1024*2);
  short* A3T = (short*)alloc((size_t)12*1024*1024*2);
  float* od  = (float*)alloc((size_t)2*12*1024*4);     // od + rab contiguous, one memset
  float* rab = od + 12*1024;
  float* rh  = (float*)alloc((size_t)64*4);
  float* dv  = (float*)alloc((size_t)12*1024*4);

  hipMemsetAsync(od, 0, (size_t)2*12*1024*4, stream);

  prep_all<<<944,256,0,stream>>>(hs, Xb, Wq, Wk, Wv, WT, g, gb);
  qkv_gemm<<<dim3(48,3),256,0,stream>>>(Xb, WT, bq,bk,bv, qs,ks,vs);
  vtrans<<<dim3(16,12),256,0,stream>>>(vs, vT);
  wg_gemm<<<dim3(64,12),256,0,stream>>>(ks, qs, gb, am, WG, od);
  rhos_k<<<12,256,0,stream>>>(od, rh);
  amat_t<<<dim3(256,12),256,0,stream>>>(WG, od, rh, Am, AmT, Tm);

  const float b1=-0.5f, b2=-0.125f, b3=-1.f/16.f, b4=-5.f/128.f, b5=-7.f/256.f;
  short* V = AmT;   // AmT dead after G2
  short* L = Tm;    // Tm dead after G3
  // G1: A2 = Am * AmT^T (= A^2)
  gemm2p_plain<<<768,256,0,stream>>>(Am, AmT, A2);
  // G2: A3T = AmT * A2^T (= (A^3)^T)
  gemm2p_plain<<<768,256,0,stream>>>(AmT, A2, A3T);
  // G3: V = T * A3 + b3 I + b4 A + b5 A2
  gemm2p_epi<<<768,256,0,stream>>>(Tm, A3T, V, Am, A2, b3,b4,b5);
  // G4: L = V * A3 + I + b1 A + b2 A2   (+ fused row |L| sums and diagonal)
  gemm2p_epi_stat<<<768,256,0,stream>>>(V, A3T, L, Am, A2, 1.0f,b1,b2, rab, dv);

  attn_k<<<dim3(16,12),256,0,stream>>>(WG, L, vT, vs, od, dv, rab, out);
}